// Round 3
// baseline (303.500 us; speedup 1.0000x reference)
//
#include <hip/hip_runtime.h>
#include <stdint.h>

typedef __attribute__((ext_vector_type(8))) short bf16x8;
typedef __attribute__((ext_vector_type(4))) float f32x4;

__device__ __forceinline__ unsigned short f2bf(float f) {
  union { float f; unsigned u; } v; v.f = f;
  unsigned u = v.u;
  u += 0x7fffu + ((u >> 16) & 1u);
  return (unsigned short)(u >> 16);
}

// B-fragment swizzle for mfma_f32_16x16x32_bf16:
// element B[k][n] lives at (((k>>5)*16 + (n>>4))*64 + (((k>>3)&3)*16 + (n&15)))*8 + (k&7)
__device__ __forceinline__ int swz_idx(int k, int n) {
  return ((((k >> 5) * 16 + (n >> 4)) * 64) + (((k >> 3) & 3) * 16 + (n & 15))) * 8 + (k & 7);
}

#define LM_STRIDE 264  // stage row stride (bf16 elems): 256 + 8 pad -> 2-way max LDS aliasing

// ---- module-scope scratch; fully rewritten every call. 16B-aligned for dwordx4 loads ----
__device__ float g_rowmean[256];
__device__ __attribute__((aligned(16))) unsigned short g_Acswz[65536];
__device__ __attribute__((aligned(16))) unsigned short g_Gswz[65536];
__device__ __attribute__((aligned(16))) unsigned short g_W3swz[65536];

// ---------------- prep kernels ----------------

__global__ void prep_rowmean(const float* __restrict__ A) {
  int f = threadIdx.x;
  float s = 0.f;
  for (int c = 0; c < 243; ++c) s += A[f * 243 + c];
  g_rowmean[f] = s * (1.f / 243.f);
}

// Acswz: B[k][n=f] = A[f][corig(k)] - rowmean[f], k-order k=(i*3+c)*9+j, pad k>=243 with 0
__global__ void prep_Ac(const float* __restrict__ A) {
  int k = blockIdx.x;   // 0..255
  int n = threadIdx.x;  // f
  float v = 0.f;
  if (k < 243) {
    int rw = k / 9, j = k - rw * 9;
    int i = rw / 3, c = rw - i * 3;
    int corig = c * 81 + i * 9 + j;
    v = A[n * 243 + corig] - g_rowmean[n];
  }
  g_Acswz[swz_idx(k, n)] = f2bf(v);
}

// Gswz: B[k=f'][n=f] = delta(f,f') - sum_c A[f,c]*Dw[c,f']   (i.e. I - (A@Dw)^T)
__global__ void prep_G(const float* __restrict__ A, const float* __restrict__ Dw) {
  int f = blockIdx.x;    // n
  int fp = threadIdx.x;  // k
  float s = 0.f;
  for (int c = 0; c < 243; ++c) s += A[f * 243 + c] * Dw[c * 256 + fp];
  float v = ((f == fp) ? 1.f : 0.f) - s;
  g_Gswz[swz_idx(fp, f)] = f2bf(v);
}

// W3swz: B[k=f][n=cc] = Ww[corig(cc)][f], pad cc>=243 with 0
__global__ void prep_W3(const float* __restrict__ Ww) {
  int cc = blockIdx.x;  // n
  int f = threadIdx.x;  // k
  float v = 0.f;
  if (cc < 243) {
    int rw = cc / 9, j = cc - rw * 9;
    int i = rw / 3, c = rw - i * 3;
    int corig = c * 81 + i * 9 + j;
    v = Ww[corig * 256 + f];
  }
  g_W3swz[swz_idx(f, cc)] = f2bf(v);
}

__global__ void zero_out(float* __restrict__ out, int n) {
  int idx = blockIdx.x * 256 + threadIdx.x;
  if (idx < n) out[idx] = 0.f;
}

// ---------------- main fused kernel ----------------
// grid: 900 blocks = 4 images * 15*15 tiles of 8x8 patch positions. 256 threads (4 waves).
// wave w handles feature chunk f in [64w, 64w+64). gamma round-trips through LDS stage.

__global__ __launch_bounds__(256, 2) void lista_fused(
    const float* __restrict__ I, const float* __restrict__ lmb, float* __restrict__ out) {
  __shared__ float img[3][16][16];
  __shared__ __attribute__((aligned(16))) unsigned short stage[64 * LM_STRIDE];
  __shared__ float meanv[64];
  __shared__ float outacc[768];
  __shared__ float lmbs[12 * 256];

  const int tid = threadIdx.x;
  const int lane = tid & 63;
  const int w = tid >> 6;
  const int m = lane & 15;
  const int q = lane >> 4;

  const int blk = blockIdx.x;
  const int b = blk / 225;
  const int t2 = blk - b * 225;
  const int ty = t2 / 15;
  const int tx = t2 - ty * 15;
  const int py0 = ty * 8, px0 = tx * 8;

  const float* Ib = I + b * (3 * 128 * 128);
  for (int r = tid; r < 768; r += 256) {
    int c = r >> 8;
    int yx = r & 255;
    int y = yx >> 4, x = yx & 15;
    img[c][y][x] = Ib[c * 16384 + (py0 + y) * 128 + (px0 + x)];
    outacc[r] = 0.f;
  }
  for (int r = tid; r < 12 * 256; r += 256) lmbs[r] = lmb[r];
  if (tid < 64) meanv[tid] = 0.f;
  __syncthreads();

  // per-position patch means (4 partial chunks of the 243-sum per position)
  {
    const int p = tid & 63;
    const int part = tid >> 6;
    const int y = p >> 3, x = p & 7;
    int k0 = part * 61;
    int k1 = k0 + 61;
    if (k1 > 243) k1 = 243;
    int rw = k0 / 9;
    int jj = k0 - rw * 9;
    int i = rw / 3, c = rw - i * 3;
    float s = 0.f;
    for (int k = k0; k < k1; ++k) {
      s += img[c][y + i][x + jj];
      if (++jj == 9) { jj = 0; if (++c == 3) { c = 0; ++i; } }
    }
    atomicAdd(&meanv[p], s * (1.f / 243.f));
  }

  f32x4 acc[4][4];
  f32x4 lin[4][4];
  const f32x4 zero = {0.f, 0.f, 0.f, 0.f};

  // ---- GEMM1: lin = patches @ Ac^T ----
  #pragma unroll
  for (int t = 0; t < 4; ++t)
    #pragma unroll
    for (int un = 0; un < 4; ++un) acc[t][un] = zero;

  #pragma unroll
  for (int s = 0; s < 8; ++s) {
    bf16x8 bf[4];
    #pragma unroll
    for (int un = 0; un < 4; ++un) {
      int u = 4 * w + un;
      bf[un] = *(const bf16x8*)(g_Acswz + (((s * 16 + u) * 64 + lane) << 3));
    }
    #pragma unroll
    for (int t = 0; t < 4; ++t) {
      int p = t * 16 + m;
      int y = p >> 3, x = p & 7;
      int k0 = s * 32 + q * 8;
      int rw = k0 / 9;
      int jj = k0 - rw * 9;
      int i = rw / 3, c = rw - i * 3;
      bf16x8 a;
      #pragma unroll
      for (int j = 0; j < 8; ++j) {
        int k = k0 + j;
        float v = 0.f;
        if (k < 243) v = img[c][y + i][x + jj];
        a[j] = (short)f2bf(v);
        if (++jj == 9) { jj = 0; if (++c == 3) { c = 0; ++i; } }
      }
      #pragma unroll
      for (int un = 0; un < 4; ++un)
        acc[t][un] = __builtin_amdgcn_mfma_f32_16x16x32_bf16(a, bf[un], acc[t][un], 0, 0, 0);
    }
  }

  // lin = acc; gamma0 = ST(lin, lmb[0]) -> stage
  #pragma unroll
  for (int un = 0; un < 4; ++un) {
    int f = 64 * w + un * 16 + m;
    float lam = lmbs[f];
    #pragma unroll
    for (int t = 0; t < 4; ++t) {
      lin[t][un] = acc[t][un];
      #pragma unroll
      for (int r = 0; r < 4; ++r) {
        float x0 = acc[t][un][r];
        float g = copysignf(fmaxf(fabsf(x0) - lam, 0.f), x0);
        stage[(t * 16 + q * 4 + r) * LM_STRIDE + f] = f2bf(g);
      }
    }
  }
  __syncthreads();

  // ---- 11 iterations: gamma <- ST(gamma @ G2 + lin, lmb[kk+1]) ----
  for (int kk = 0; kk < 11; ++kk) {
    #pragma unroll
    for (int t = 0; t < 4; ++t)
      #pragma unroll
      for (int un = 0; un < 4; ++un) acc[t][un] = lin[t][un];

    #pragma unroll
    for (int s = 0; s < 8; ++s) {
      bf16x8 bf[4];
      #pragma unroll
      for (int un = 0; un < 4; ++un) {
        int u = 4 * w + un;
        bf[un] = *(const bf16x8*)(g_Gswz + (((s * 16 + u) * 64 + lane) << 3));
      }
      #pragma unroll
      for (int t = 0; t < 4; ++t) {
        bf16x8 a = *(const bf16x8*)(&stage[(t * 16 + m) * LM_STRIDE + s * 32 + q * 8]);
        #pragma unroll
        for (int un = 0; un < 4; ++un)
          acc[t][un] = __builtin_amdgcn_mfma_f32_16x16x32_bf16(a, bf[un], acc[t][un], 0, 0, 0);
      }
    }
    __syncthreads();  // all stage (gamma_k) reads done
    #pragma unroll
    for (int un = 0; un < 4; ++un) {
      int f = 64 * w + un * 16 + m;
      float lam = lmbs[(kk + 1) * 256 + f];
      #pragma unroll
      for (int t = 0; t < 4; ++t)
        #pragma unroll
        for (int r = 0; r < 4; ++r) {
          float x0 = acc[t][un][r];
          float g = copysignf(fmaxf(fabsf(x0) - lam, 0.f), x0);
          stage[(t * 16 + q * 4 + r) * LM_STRIDE + f] = f2bf(g);
        }
    }
    __syncthreads();  // gamma_{k+1} visible
  }

  // ---- GEMM3: out_cols = gamma @ W3 (+ mean), fold into outacc ----
  #pragma unroll
  for (int t = 0; t < 4; ++t)
    #pragma unroll
    for (int un = 0; un < 4; ++un) acc[t][un] = zero;

  #pragma unroll
  for (int s = 0; s < 8; ++s) {
    bf16x8 bf[4];
    #pragma unroll
    for (int un = 0; un < 4; ++un) {
      int u = 4 * w + un;
      bf[un] = *(const bf16x8*)(g_W3swz + (((s * 16 + u) * 64 + lane) << 3));
    }
    #pragma unroll
    for (int t = 0; t < 4; ++t) {
      bf16x8 a = *(const bf16x8*)(&stage[(t * 16 + m) * LM_STRIDE + s * 32 + q * 8]);
      #pragma unroll
      for (int un = 0; un < 4; ++un)
        acc[t][un] = __builtin_amdgcn_mfma_f32_16x16x32_bf16(a, bf[un], acc[t][un], 0, 0, 0);
    }
  }

  #pragma unroll
  for (int un = 0; un < 4; ++un) {
    int cc = 64 * w + un * 16 + m;
    if (cc < 243) {
      int rw = cc / 9, jj = cc - rw * 9;
      int i = rw / 3, c = rw - i * 3;
      #pragma unroll
      for (int t = 0; t < 4; ++t)
        #pragma unroll
        for (int r = 0; r < 4; ++r) {
          int pos = t * 16 + q * 4 + r;
          int y = (pos >> 3) + i, x = (pos & 7) + jj;
          float val = acc[t][un][r] + meanv[pos];
          atomicAdd(&outacc[c * 256 + y * 16 + x], val);
        }
    }
  }
  __syncthreads();

  float* Ob = out + b * (3 * 128 * 128);
  for (int r = tid; r < 768; r += 256) {
    int c = r >> 8;
    int yx = r & 255;
    int y = yx >> 4, x = yx & 15;
    atomicAdd(&Ob[c * 16384 + (py0 + y) * 128 + (px0 + x)], outacc[r]);
  }
}

// divide by overlap counts
__global__ void div_counts(float* __restrict__ out, int n) {
  int idx = blockIdx.x * 256 + threadIdx.x;
  if (idx >= n) return;
  int x = idx & 127, y = (idx >> 7) & 127;
  int loy = y - 8; if (loy < 0) loy = 0;
  int hiy = y; if (hiy > 119) hiy = 119;
  int lox = x - 8; if (lox < 0) lox = 0;
  int hix = x; if (hix > 119) hix = 119;
  float cnt = (float)((hiy - loy + 1) * (hix - lox + 1));
  out[idx] = out[idx] / cnt;
}

extern "C" void kernel_launch(void* const* d_in, const int* in_sizes, int n_in,
                              void* d_out, int out_size, void* d_ws, size_t ws_size,
                              hipStream_t stream) {
  const float* I = (const float*)d_in[0];
  const float* A = (const float*)d_in[1];
  const float* Dw = (const float*)d_in[2];
  const float* Ww = (const float*)d_in[3];
  const float* lmb = (const float*)d_in[4];
  float* out = (float*)d_out;
  (void)d_ws; (void)ws_size;

  const int nblk = (out_size + 255) / 256;  // out_size = 196608 -> 768 blocks
  zero_out<<<nblk, 256, 0, stream>>>(out, out_size);
  prep_rowmean<<<1, 256, 0, stream>>>(A);
  prep_Ac<<<256, 256, 0, stream>>>(A);
  prep_G<<<256, 256, 0, stream>>>(A, Dw);
  prep_W3<<<256, 256, 0, stream>>>(Ww);
  lista_fused<<<900, 256, 0, stream>>>(I, lmb, out);
  div_counts<<<nblk, 256, 0, stream>>>(out, out_size);
}